// Round 20
// baseline (627.318 us; speedup 1.0000x reference)
//
#include <hip/hip_runtime.h>
#include <math.h>

#define B_ 2
#define T_ 128
#define F_ 88
#define HID 64
#define NU 64
#define NH 4
#define HD 16
#define LH 32
#define NSEQ (B_*F_)
#define NTOK (B_*T_*F_)
#define NPOS (T_*F_)

__device__ __forceinline__ float fsig(float x) {
    return __builtin_amdgcn_rcpf(1.0f + __expf(-x));
}
__device__ __forceinline__ float ftanh(float x) {
    return 2.0f * __builtin_amdgcn_rcpf(1.0f + __expf(-2.0f*x)) - 1.0f;
}

// ---------------------------------------------------------------------------
// FUSED gate-GEMM + LSTM recurrence. Block = seq, 128 thr = 2 waves (dirs).
// Thread (dir,lane) owns gate rows {lane, 64+lane}: it PRODUCES their
// pre-activations (W_ih rows in registers, x chunk staged in a 4-slot LDS
// ring, uniform-address reads) for the 4-step group two ahead, and CONSUMES
// them in the r15-proven recurrence (h broadcast via hstage LDS uniform read).
// Production FMAs fill the recurrence's stall slots. Zero G global traffic.
// ---------------------------------------------------------------------------
template<int LAYER>
__global__ void __launch_bounds__(128, 1) lstm_fused(
    const float* __restrict__ xin,   // L0: x (B,T,F,64); L1: h0 (NSEQ,T,64)
    const float* __restrict__ w_ih,  // (2,2,128,64)
    const float* __restrict__ w_hh,  // (2,2,128,32)
    const float* __restrict__ b_ih,  // (2,2,128)
    const float* __restrict__ b_hh,  // (2,2,128)
    float* __restrict__ outp)        // L0: (NSEQ,T,64); L1: (B,T,F,64)
{
    __shared__ float hbuf[T_][NU];                    // 32 KB
    __shared__ __align__(16) float hstage[2][LH];     // h broadcast slot
    __shared__ __align__(16) float xstage[2][4][4][64]; // x ring, 8 KB
    const int s = blockIdx.x;
    const int b = s / F_, f = s % F_;
    const int lane = threadIdx.x & 63;
    const int dir  = threadIdx.x >> 6;

    // W_ih rows lane (A) and 64+lane (B) in registers; biases
    float wA[64], wB[64];
    {
        const float* wbase = w_ih + (size_t)((LAYER*2+dir)*128)*HID;
        const float4* pa = (const float4*)(wbase + (size_t)lane*HID);
        const float4* pb = (const float4*)(wbase + (size_t)(64+lane)*HID);
        #pragma unroll
        for (int q = 0; q < 16; q++) {
            float4 a = pa[q], bq = pb[q];
            wA[q*4+0]=a.x;  wA[q*4+1]=a.y;  wA[q*4+2]=a.z;  wA[q*4+3]=a.w;
            wB[q*4+0]=bq.x; wB[q*4+1]=bq.y; wB[q*4+2]=bq.z; wB[q*4+3]=bq.w;
        }
    }
    const int brow = (LAYER*2+dir)*128;
    const float biasA = b_ih[brow + lane]      + b_hh[brow + lane];
    const float biasB = b_ih[brow + 64 + lane] + b_hh[brow + 64 + lane];

    // W_hh interleaved (r15 layout)
    float2 wh2[LH];
    {
        const float4* pa = (const float4*)(w_hh + ((size_t)(LAYER*2+dir)*128 + lane)*LH);
        const float4* pb = (const float4*)(w_hh + ((size_t)(LAYER*2+dir)*128 + 64 + lane)*LH);
        #pragma unroll
        for (int k4 = 0; k4 < LH/4; k4++) {
            float4 a = pa[k4], c4 = pb[k4];
            wh2[k4*4+0].x=a.x; wh2[k4*4+0].y=c4.x;
            wh2[k4*4+1].x=a.y; wh2[k4*4+1].y=c4.y;
            wh2[k4*4+2].x=a.z; wh2[k4*4+2].y=c4.z;
            wh2[k4*4+3].x=a.w; wh2[k4*4+3].y=c4.w;
        }
    }

    const float a1 = (lane < LH) ? 2.f : 1.f;
    const float c1 = (lane < LH) ? -1.f : 0.f;
    float h = 0.f, c = 0.f;
    if (lane < LH) hstage[dir][lane] = 0.f;

    #define GTIME(st) (dir ? (T_-1-(st)) : (st))
    // x chunk loader: lane covers (tt = lane>>4, k4 = (lane&15)*4)
    const int xtt = lane >> 4;
    const int xk4 = (lane & 15) * 4;
    #define XADDR(t) ((LAYER==0) ? ((((size_t)b*T_+(t))*F_ + f)*HID + xk4) \
                                 : (((size_t)s*T_+(t))*HID + xk4))
    #define LOADX(g) (*(const float4*)&xin[XADDR(GTIME(min((g)*4+xtt, T_-1)))])
    #define STOREX(slot, v) { *(float4*)&xstage[dir][slot][xtt][xk4] = (v); }

    #define PRODUCE(slot, GA, GB)                                            \
    {                                                                        \
        _Pragma("unroll")                                                    \
        for (int tt = 0; tt < 4; tt++) {                                     \
            float pa0 = biasA, pb0 = biasB, pa1 = 0.f, pb1 = 0.f;            \
            _Pragma("unroll")                                                \
            for (int q = 0; q < 8; q++) {                                    \
                const float4 xv = *(const float4*)&xstage[dir][slot][tt][q*8];   \
                const float4 xw = *(const float4*)&xstage[dir][slot][tt][q*8+4]; \
                pa0 += wA[q*8+0]*xv.x + wA[q*8+1]*xv.y                       \
                     + wA[q*8+2]*xv.z + wA[q*8+3]*xv.w;                      \
                pb0 += wB[q*8+0]*xv.x + wB[q*8+1]*xv.y                       \
                     + wB[q*8+2]*xv.z + wB[q*8+3]*xv.w;                      \
                pa1 += wA[q*8+4]*xw.x + wA[q*8+5]*xw.y                       \
                     + wA[q*8+6]*xw.z + wA[q*8+7]*xw.w;                      \
                pb1 += wB[q*8+4]*xw.x + wB[q*8+5]*xw.y                       \
                     + wB[q*8+6]*xw.z + wB[q*8+7]*xw.w;                      \
            }                                                                \
            GA[tt] = pa0 + pa1; GB[tt] = pb0 + pb1;                          \
        }                                                                    \
    }

    #define STEP(gAv, gBv, stepi)                                            \
    {                                                                        \
        float hbc[LH];                                                       \
        _Pragma("unroll")                                                    \
        for (int q = 0; q < LH/4; q++) {                                     \
            const float4 hv = *(const float4*)&hstage[dir][q*4];             \
            hbc[q*4+0]=hv.x; hbc[q*4+1]=hv.y;                                \
            hbc[q*4+2]=hv.z; hbc[q*4+3]=hv.w;                                \
        }                                                                    \
        float aA0 = (gAv), aB0 = (gBv), aA1 = 0.f, aB1 = 0.f;                \
        _Pragma("unroll")                                                    \
        for (int k = 0; k < 16; k++) {                                       \
            aA0 += wh2[k].x*hbc[k];      aB0 += wh2[k].y*hbc[k];             \
            aA1 += wh2[k+16].x*hbc[k+16]; aB1 += wh2[k+16].y*hbc[k+16];      \
        }                                                                    \
        const float accA = aA0 + aA1, accB = aB0 + aB1;                      \
        const float e0 = fsig(accA);                                         \
        const float e1 = fmaf(a1, fsig(a1*accB), c1);                        \
        const float x0 = __shfl_xor(e0, 32, 64);                             \
        const float x1 = __shfl_xor(e1, 32, 64);                             \
        c = x0*c + e0*e1;                                                    \
        h = x1 * ftanh(c);                                                   \
        if (lane < LH) {                                                     \
            hbuf[GTIME(stepi)][dir*LH + lane] = h;                           \
            hstage[dir][lane] = h;                                           \
        }                                                                    \
    }

    // prologue: stage x for groups 0..2, produce groups 0 and 1
    {
        float4 t0 = LOADX(0), t1 = LOADX(1), t2 = LOADX(2);
        STOREX(0, t0); STOREX(1, t1); STOREX(2, t2);
    }
    float AA[4], AB[4], BA[4], BB[4];
    PRODUCE(0, AA, AB);
    PRODUCE(1, BA, BB);
    float4 xreg = LOADX(3);

    #pragma unroll 1
    for (int grp = 0; grp < 32; grp++) {
        STOREX((grp+3)&3, xreg);              // x for group grp+3 into ring
        float PA[4], PB[4];
        PRODUCE((grp+2)&3, PA, PB);           // pre-activations for grp+2
        xreg = LOADX(grp+4 < 32 ? grp+4 : 31);
        #pragma unroll
        for (int i = 0; i < 4; i++) { STEP(AA[i], AB[i], grp*4 + i); }
        #pragma unroll
        for (int i = 0; i < 4; i++) {
            AA[i]=BA[i]; AB[i]=BB[i]; BA[i]=PA[i]; BB[i]=PB[i];
        }
    }
    #undef STEP
    #undef PRODUCE
    #undef STOREX
    #undef LOADX
    #undef XADDR
    #undef GTIME
    __syncthreads();

    const int tid = threadIdx.x;
    const float4* lds4 = (const float4*)&hbuf[0][0];
    if (LAYER == 0) {
        float4* out4 = (float4*)outp + (size_t)s*T_*16;
        #pragma unroll
        for (int it = 0; it < 16; it++)
            out4[it*128 + tid] = lds4[it*128 + tid];
    } else {
        const int c4 = tid & 15, trow = tid >> 4;
        #pragma unroll
        for (int it = 0; it < 16; it++) {
            const int t = it*8 + trow;
            ((float4*)outp)[(((size_t)b*T_ + t)*F_ + f)*16 + c4] = lds4[t*16 + c4];
        }
    }
}

// ---------------------------------------------------------------------------
// qkv GEMM (r15-proven split form, grid (NTOK/64, 3))
// ---------------------------------------------------------------------------
__global__ void __launch_bounds__(256, 2) qkv_kernel(
    const float* __restrict__ hcur,  // (NTOK,64)
    const int*   __restrict__ tarr,  // (B)
    const float* __restrict__ t_emb, // (2,100,64)
    const float* __restrict__ w_qkv, // (2,64,192)
    const float* __restrict__ b_qkv, // (2,192)
    const int layer,
    float* __restrict__ qb, float* __restrict__ kb, float* __restrict__ vb)
{
    __shared__ float as[64][65];
    __shared__ float wsh[64][64];
    const int m0 = blockIdx.x * 64;
    const int which = blockIdx.y;
    const int tid = threadIdx.x;
    const int bidx = m0 / NPOS;
    const int tb = tarr[bidx];
    const float* embp = t_emb + ((size_t)layer*100 + tb)*HID;

    for (int n = tid; n < 64*64; n += 256) {
        const int mm = n >> 6, k = n & 63;
        as[mm][k]  = hcur[((size_t)m0+mm)*64 + k] + embp[k];
        wsh[mm][k] = w_qkv[((size_t)layer*64 + mm)*192 + which*64 + k];
    }
    __syncthreads();

    const int tm = tid >> 4, tn = tid & 15;
    float acc[4][4] = {};
    for (int k = 0; k < 64; k++) {
        const float a0 = as[tm*4+0][k];
        const float a1 = as[tm*4+1][k];
        const float a2 = as[tm*4+2][k];
        const float a3 = as[tm*4+3][k];
        const float4 w = *(const float4*)&wsh[k][tn*4];
        acc[0][0]+=a0*w.x; acc[0][1]+=a0*w.y; acc[0][2]+=a0*w.z; acc[0][3]+=a0*w.w;
        acc[1][0]+=a1*w.x; acc[1][1]+=a1*w.y; acc[1][2]+=a1*w.z; acc[1][3]+=a1*w.w;
        acc[2][0]+=a2*w.x; acc[2][1]+=a2*w.y; acc[2][2]+=a2*w.z; acc[2][3]+=a2*w.w;
        acc[3][0]+=a3*w.x; acc[3][1]+=a3*w.y; acc[3][2]+=a3*w.z; acc[3][3]+=a3*w.w;
    }

    float* dst = (which == 0) ? qb : (which == 1) ? kb : vb;
    const float scale = (which == 0) ? 0.25f : 1.0f;   // HEAD_DIM^-0.5
    const int hh = tn >> 2;
    const int dbase = (tn & 3) * 4;
    const float4 bv = *(const float4*)&b_qkv[(size_t)layer*192 + which*64 + tn*4];
    #pragma unroll
    for (int r = 0; r < 4; r++) {
        const int row = m0 + tm*4 + r;
        const int pos = row - bidx*NPOS;
        float4 o;
        o.x = (acc[r][0] + bv.x) * scale;
        o.y = (acc[r][1] + bv.y) * scale;
        o.z = (acc[r][2] + bv.z) * scale;
        o.w = (acc[r][3] + bv.w) * scale;
        *(float4*)&dst[(((size_t)bidx*NH + hh)*NPOS + pos)*HD + dbase] = o;
    }
}

// ---------------------------------------------------------------------------
// Neighborhood attention v5 (r14-proven): block = (bh, 4 query rows), k/v
// co-staged fp32 into LDS (141 KB) in one loop -> single barrier.
// blockIdx = it*8+bh keeps (b,h) per-XCD.
// ---------------------------------------------------------------------------
__global__ void __launch_bounds__(384, 1) nattn_kernel(
    const float* __restrict__ qb,
    const float* __restrict__ kb,
    const float* __restrict__ vb,
    const float* __restrict__ rpb,   // (2,4,13,13)
    const int layer,
    float* __restrict__ ao)          // (B,T,F,64)
{
    __shared__ float kv[2][10][88][20];   // 140.8 KB
    __shared__ float rp[169];
    const int blk = blockIdx.x;
    const int bh = blk & 7;          // XCD selector under round-robin dispatch
    const int it = blk >> 3;         // 0..31
    const int i0 = it*4;
    const int h  = bh & 3;
    const int bb = bh >> 2;
    const int tid = threadIdx.x;
    const int rs = min(max(i0-3, 0), T_-10);   // 10-row window start
    const float* kbase = kb + (size_t)bh*NPOS*HD;
    const float* vbase = vb + (size_t)bh*NPOS*HD;

    const bool act = (tid < 4*F_);
    const int isub = act ? (tid / F_) : 0;
    const int j    = act ? (tid - isub*F_) : 0;
    const int i    = i0 + isub;
    const int ihs  = min(max(i-3, 0), T_-7);
    const int ro   = ihs - rs;       // 0..3: local row offset
    const int cw   = min(max(j-3, 0), F_-7);

    float4 q0, q1, q2, q3;
    if (act) {
        const float4* qp = (const float4*)&qb[((size_t)bh*NPOS + i*F_ + j)*HD];
        q0 = qp[0]; q1 = qp[1]; q2 = qp[2]; q3 = qp[3];
    }
    for (int n = tid; n < 169; n += 384)
        rp[n] = rpb[((size_t)layer*NH + h)*169 + n];
    for (int n4 = tid; n4 < 10*88*4; n4 += 384) {
        const int d4   = n4 & 3;
        const int rest = n4 >> 2;
        const int c    = rest % 88;
        const int r    = rest / 88;
        const size_t goff = ((size_t)(rs+r)*F_ + c)*HD + d4*4;
        *(float4*)&kv[0][r][c][d4*4] = *(const float4*)&kbase[goff];
        *(float4*)&kv[1][r][c][d4*4] = *(const float4*)&vbase[goff];
    }
    __syncthreads();

    if (act) {
        float lg[49];
        #pragma unroll
        for (int ki = 0; ki < 7; ki++) {
            const int rh = ihs + ki - i + 6;
            #pragma unroll
            for (int kj = 0; kj < 7; kj++) {
                const float4* kp = (const float4*)&kv[0][ro+ki][cw+kj][0];
                const float4 k0 = kp[0], k1 = kp[1], k2 = kp[2], k3 = kp[3];
                float d = q0.x*k0.x + q0.y*k0.y + q0.z*k0.z + q0.w*k0.w
                        + q1.x*k1.x + q1.y*k1.y + q1.z*k1.z + q1.w*k1.w
                        + q2.x*k2.x + q2.y*k2.y + q2.z*k2.z + q2.w*k2.w
                        + q3.x*k3.x + q3.y*k3.y + q3.z*k3.z + q3.w*k3.w;
                lg[ki*7+kj] = d + rp[rh*13 + (cw + kj - j + 6)];
            }
        }
        float m = lg[0];
        #pragma unroll
        for (int n = 1; n < 49; n++) m = fmaxf(m, lg[n]);
        float ssum = 0.f;
        #pragma unroll
        for (int n = 0; n < 49; n++) { lg[n] = __expf(lg[n] - m); ssum += lg[n]; }
        const float inv = __builtin_amdgcn_rcpf(ssum);
        #pragma unroll
        for (int n = 0; n < 49; n++) lg[n] *= inv;

        float4 o0 = {0,0,0,0}, o1 = {0,0,0,0}, o2 = {0,0,0,0}, o3 = {0,0,0,0};
        #pragma unroll
        for (int ki = 0; ki < 7; ki++) {
            #pragma unroll
            for (int kj = 0; kj < 7; kj++) {
                const float a = lg[ki*7+kj];
                const float4* vp = (const float4*)&kv[1][ro+ki][cw+kj][0];
                const float4 v0 = vp[0], v1 = vp[1], v2 = vp[2], v3 = vp[3];
                o0.x += a*v0.x; o0.y += a*v0.y; o0.z += a*v0.z; o0.w += a*v0.w;
                o1.x += a*v1.x; o1.y += a*v1.y; o1.z += a*v1.z; o1.w += a*v1.w;
                o2.x += a*v2.x; o2.y += a*v2.y; o2.z += a*v2.z; o2.w += a*v2.w;
                o3.x += a*v3.x; o3.y += a*v3.y; o3.z += a*v3.z; o3.w += a*v3.w;
            }
        }
        float4* op = (float4*)&ao[(((size_t)bb*T_ + i)*F_ + j)*NU + h*HD];
        op[0]=o0; op[1]=o1; op[2]=o2; op[3]=o3;
    }
}

// ---------------------------------------------------------------------------
// proj + residual: out = hres + ain @ Wproj + b  (unchanged)
// ---------------------------------------------------------------------------
__global__ void __launch_bounds__(256, 2) proj_kernel(
    const float* __restrict__ ain,   // (NTOK,64)
    const float* __restrict__ hres,  // (NTOK,64)
    const float* __restrict__ w_proj,// (2,64,64)
    const float* __restrict__ b_proj,// (2,64)
    const int layer,
    float* __restrict__ outp)
{
    __shared__ float as[64][65];
    __shared__ float wsh[64][64];
    const int m0 = blockIdx.x * 64;
    const int tid = threadIdx.x;
    for (int n = tid; n < 64*64; n += 256) {
        const int mm = n >> 6, k = n & 63;
        as[mm][k]  = ain[((size_t)m0+mm)*64 + k];
        wsh[mm][k] = w_proj[(size_t)layer*4096 + n];
    }
    __syncthreads();
    const int tm = tid >> 4, tn = tid & 15;
    float acc[4][4] = {};
    for (int k = 0; k < 64; k++) {
        const float a0 = as[tm*4+0][k];
        const float a1 = as[tm*4+1][k];
        const float a2 = as[tm*4+2][k];
        const float a3 = as[tm*4+3][k];
        const float4 w = *(const float4*)&wsh[k][tn*4];
        acc[0][0]+=a0*w.x; acc[0][1]+=a0*w.y; acc[0][2]+=a0*w.z; acc[0][3]+=a0*w.w;
        acc[1][0]+=a1*w.x; acc[1][1]+=a1*w.y; acc[1][2]+=a1*w.z; acc[1][3]+=a1*w.w;
        acc[2][0]+=a2*w.x; acc[2][1]+=a2*w.y; acc[2][2]+=a2*w.z; acc[2][3]+=a2*w.w;
        acc[3][0]+=a3*w.x; acc[3][1]+=a3*w.y; acc[3][2]+=a3*w.z; acc[3][3]+=a3*w.w;
    }
    const float4 bv = *(const float4*)&b_proj[(size_t)layer*64 + tn*4];
    #pragma unroll
    for (int r = 0; r < 4; r++) {
        const int row = m0 + tm*4 + r;
        const float4 hv = *(const float4*)&hres[(size_t)row*64 + tn*4];
        float4 o;
        o.x = hv.x + acc[r][0] + bv.x;
        o.y = hv.y + acc[r][1] + bv.y;
        o.z = hv.z + acc[r][2] + bv.z;
        o.w = hv.w + acc[r][3] + bv.w;
        *(float4*)&outp[(size_t)row*64 + tn*4] = o;
    }
}

extern "C" void kernel_launch(void* const* d_in, const int* in_sizes, int n_in,
                              void* d_out, int out_size, void* d_ws, size_t ws_size,
                              hipStream_t stream) {
    const float* x      = (const float*)d_in[0];
    const int*   tarr   = (const int*)  d_in[1];
    const float* w_ih   = (const float*)d_in[2];
    const float* w_hh   = (const float*)d_in[3];
    const float* b_ih   = (const float*)d_in[4];
    const float* b_hh   = (const float*)d_in[5];
    const float* t_emb  = (const float*)d_in[6];
    const float* w_qkv  = (const float*)d_in[7];
    const float* b_qkv  = (const float*)d_in[8];
    const float* rpb    = (const float*)d_in[9];
    const float* w_proj = (const float*)d_in[10];
    const float* b_proj = (const float*)d_in[11];

    float* ws   = (float*)d_ws;
    const size_t CH = (size_t)NTOK * NU;   // 1441792 floats
    float* hcur = ws;                      // (B,T,F,64)
    float* h0   = ws + CH;                 // (NSEQ,T,64)
    float* qbuf = ws + 2*CH;
    float* kbuf = ws + 3*CH;
    float* vbuf = ws + 4*CH;
    float* ao   = ws + 5*CH;
    float* outp = (float*)d_out;

    lstm_fused<0><<<NSEQ, 128, 0, stream>>>(x,  w_ih, w_hh, b_ih, b_hh, h0);
    lstm_fused<1><<<NSEQ, 128, 0, stream>>>(h0, w_ih, w_hh, b_ih, b_hh, hcur);

    for (int l = 0; l < 2; l++) {
        qkv_kernel<<<dim3(NTOK/64, 3), 256, 0, stream>>>(
            hcur, tarr, t_emb, w_qkv, b_qkv, l, qbuf, kbuf, vbuf);
        nattn_kernel<<<(T_/4)*8, 384, 0, stream>>>(
            qbuf, kbuf, vbuf, rpb, l, ao);
        proj_kernel<<<NTOK/64, 256, 0, stream>>>(
            ao, hcur, w_proj, b_proj, l, (l == 0) ? hcur : outp);
    }
}

// Round 21
// 241.257 us; speedup vs baseline: 2.6002x; 2.6002x over previous
//
#include <hip/hip_runtime.h>
#include <math.h>

#define B_ 2
#define T_ 128
#define F_ 88
#define HID 64
#define NU 64
#define NH 4
#define HD 16
#define LH 32
#define NSEQ (B_*F_)
#define NTOK (B_*T_*F_)
#define NPOS (T_*F_)

__device__ __forceinline__ float fsig(float x) {
    return __builtin_amdgcn_rcpf(1.0f + __expf(-x));
}
__device__ __forceinline__ float ftanh(float x) {
    return 2.0f * __builtin_amdgcn_rcpf(1.0f + __expf(-2.0f*x)) - 1.0f;
}

// ---------------------------------------------------------------------------
// Gate pre-activation GEMM (r9-proven). G packed as float2 per (s,dir,t,lane).
// ---------------------------------------------------------------------------
template<int LAYER>
__global__ void __launch_bounds__(256, 2) gg_kernel(
    const float* __restrict__ xin,   // L0: x (B,T,F,64); L1: h0 (NSEQ,T,64)
    const float* __restrict__ w_ih,  // (2,2,128,64)
    const float* __restrict__ b_ih,  // (2,2,128)
    const float* __restrict__ b_hh,  // (2,2,128)
    float* __restrict__ G)           // (NSEQ,2,T,64) float2
{
    __shared__ __align__(16) float xts[32][68];
    __shared__ __align__(16) float wsh[256][68];
    __shared__ float bsh[256];
    const int s  = blockIdx.x;
    const int t0 = blockIdx.y * 32;
    const int b = s / F_, f = s % F_;
    const int tid = threadIdx.x;

    for (int n = tid; n < 32*64; n += 256) {
        const int tt = n >> 6, k = n & 63;
        xts[tt][k] = (LAYER == 0)
            ? xin[(((size_t)b*T_ + t0+tt)*F_ + f)*HID + k]
            : xin[((size_t)s*T_ + t0+tt)*HID + k];
    }
    for (int n = tid; n < 256*64; n += 256) {
        const int row = n >> 6, k = n & 63;
        wsh[row][k] = w_ih[((size_t)LAYER*256 + row)*HID + k];
    }
    bsh[tid] = b_ih[LAYER*256 + tid] + b_hh[LAYER*256 + tid];
    __syncthreads();

    const int lane = tid & 63;
    const int g    = tid >> 6;      // 0..3
    const int dir  = g >> 1;
    const int th   = g & 1;         // which 16-timestep half
    const int rowA = dir*128 + lane;
    const int rowB = dir*128 + 64 + lane;

    float accA[16] = {}, accB[16] = {};
    #pragma unroll 4
    for (int k4 = 0; k4 < 16; k4++) {
        const float4 wA = *(const float4*)&wsh[rowA][k4*4];
        const float4 wB = *(const float4*)&wsh[rowB][k4*4];
        #pragma unroll
        for (int tt = 0; tt < 16; tt++) {
            const float4 xv = *(const float4*)&xts[th*16+tt][k4*4];
            accA[tt] += wA.x*xv.x + wA.y*xv.y + wA.z*xv.z + wA.w*xv.w;
            accB[tt] += wB.x*xv.x + wB.y*xv.y + wB.z*xv.z + wB.w*xv.w;
        }
    }
    const float bA = bsh[rowA], bB = bsh[rowB];
    float2* gout = (float2*)G + ((size_t)(s*2+dir)*T_ + t0 + th*16)*64 + lane;
    #pragma unroll
    for (int tt = 0; tt < 16; tt++) {
        float2 o; o.x = accA[tt] + bA; o.y = accB[tt] + bB;
        gout[(size_t)tt*64] = o;
    }
}

// ---------------------------------------------------------------------------
// LSTM recurrence v9 (r15-proven): h broadcast via LDS uniform-address read.
// Parked at measured floor (~49 us) after r5-r20 exploration (8 falsified
// structural variants bracket this as the serial-latency optimum).
// ---------------------------------------------------------------------------
template<int LAYER>
__global__ void __launch_bounds__(128, 1) lstm_rec(
    const float* __restrict__ G,     // (NSEQ,2,T,64) float2
    const float* __restrict__ w_hh,  // (2,2,128,32)
    float* __restrict__ outp)        // L0: (NSEQ,T,64); L1: (B,T,F,64)
{
    __shared__ float hbuf[T_][NU];   // 32 KB
    __shared__ __align__(16) float hstage[2][LH];
    const int s = blockIdx.x;
    const int b = s / F_, f = s % F_;
    const int lane = threadIdx.x & 63;
    const int dir  = threadIdx.x >> 6;

    float2 wh2[LH];
    {
        const float4* pa = (const float4*)(w_hh + ((size_t)(LAYER*2+dir)*128 + lane)*LH);
        const float4* pb = (const float4*)(w_hh + ((size_t)(LAYER*2+dir)*128 + 64 + lane)*LH);
        #pragma unroll
        for (int k4 = 0; k4 < LH/4; k4++) {
            float4 a = pa[k4], c4 = pb[k4];
            wh2[k4*4+0].x=a.x; wh2[k4*4+0].y=c4.x;
            wh2[k4*4+1].x=a.y; wh2[k4*4+1].y=c4.y;
            wh2[k4*4+2].x=a.z; wh2[k4*4+2].y=c4.z;
            wh2[k4*4+3].x=a.w; wh2[k4*4+3].y=c4.w;
        }
    }
    const float2* gp = (const float2*)G + (size_t)(s*2+dir)*T_*64 + lane;
    #define GTIME(st) (dir ? (T_-1-(st)) : (st))

    const float a1 = (lane < LH) ? 2.f : 1.f;
    const float c1 = (lane < LH) ? -1.f : 0.f;

    float h = 0.f, c = 0.f;
    if (lane < LH) hstage[dir][lane] = 0.f;

    #define STEP(gAv, gBv, stepi)                                            \
    {                                                                        \
        float hbc[LH];                                                       \
        _Pragma("unroll")                                                    \
        for (int q = 0; q < LH/4; q++) {                                     \
            const float4 hv = *(const float4*)&hstage[dir][q*4];             \
            hbc[q*4+0]=hv.x; hbc[q*4+1]=hv.y;                                \
            hbc[q*4+2]=hv.z; hbc[q*4+3]=hv.w;                                \
        }                                                                    \
        float aA0 = (gAv), aB0 = (gBv), aA1 = 0.f, aB1 = 0.f;                \
        _Pragma("unroll")                                                    \
        for (int k = 0; k < 16; k++) {                                       \
            aA0 += wh2[k].x*hbc[k];      aB0 += wh2[k].y*hbc[k];             \
            aA1 += wh2[k+16].x*hbc[k+16]; aB1 += wh2[k+16].y*hbc[k+16];      \
        }                                                                    \
        const float accA = aA0 + aA1, accB = aB0 + aB1;                      \
        const float e0 = fsig(accA);                                         \
        const float e1 = fmaf(a1, fsig(a1*accB), c1);                        \
        const float x0 = __shfl_xor(e0, 32, 64);                             \
        const float x1 = __shfl_xor(e1, 32, 64);                             \
        c = x0*c + e0*e1;                                                    \
        h = x1 * ftanh(c);                                                   \
        if (lane < LH) {                                                     \
            hbuf[GTIME(stepi)][dir*LH + lane] = h;                           \
            hstage[dir][lane] = h;                                           \
        }                                                                    \
    }

    float2 A[4], Bf[4];
    #pragma unroll
    for (int i = 0; i < 4; i++) A[i]  = gp[(size_t)GTIME(i)*64];
    #pragma unroll
    for (int i = 0; i < 4; i++) Bf[i] = gp[(size_t)GTIME(4+i)*64];

    #pragma unroll 1
    for (int grp = 0; grp < 32; grp++) {
        float2 P[4];
        const int pf = (grp < 30 ? grp + 2 : 31) * 4;
        #pragma unroll
        for (int i = 0; i < 4; i++) P[i] = gp[(size_t)GTIME(pf+i)*64];
        #pragma unroll
        for (int i = 0; i < 4; i++) { STEP(A[i].x, A[i].y, grp*4 + i); }
        #pragma unroll
        for (int i = 0; i < 4; i++) { A[i] = Bf[i]; Bf[i] = P[i]; }
    }
    #undef STEP
    #undef GTIME
    __syncthreads();

    const int tid = threadIdx.x;
    const float4* lds4 = (const float4*)&hbuf[0][0];
    if (LAYER == 0) {
        float4* out4 = (float4*)outp + (size_t)s*T_*16;
        #pragma unroll
        for (int it = 0; it < 16; it++)
            out4[it*128 + tid] = lds4[it*128 + tid];
    } else {
        const int c4 = tid & 15, trow = tid >> 4;
        #pragma unroll
        for (int it = 0; it < 16; it++) {
            const int t = it*8 + trow;
            ((float4*)outp)[(((size_t)b*T_ + t)*F_ + f)*16 + c4] = lds4[t*16 + c4];
        }
    }
}

// ---------------------------------------------------------------------------
// qkv GEMM (r15-proven split form, grid (NTOK/64, 3))
// ---------------------------------------------------------------------------
__global__ void __launch_bounds__(256, 2) qkv_kernel(
    const float* __restrict__ hcur,  // (NTOK,64)
    const int*   __restrict__ tarr,  // (B)
    const float* __restrict__ t_emb, // (2,100,64)
    const float* __restrict__ w_qkv, // (2,64,192)
    const float* __restrict__ b_qkv, // (2,192)
    const int layer,
    float* __restrict__ qb, float* __restrict__ kb, float* __restrict__ vb)
{
    __shared__ float as[64][65];
    __shared__ float wsh[64][64];
    const int m0 = blockIdx.x * 64;
    const int which = blockIdx.y;
    const int tid = threadIdx.x;
    const int bidx = m0 / NPOS;
    const int tb = tarr[bidx];
    const float* embp = t_emb + ((size_t)layer*100 + tb)*HID;

    for (int n = tid; n < 64*64; n += 256) {
        const int mm = n >> 6, k = n & 63;
        as[mm][k]  = hcur[((size_t)m0+mm)*64 + k] + embp[k];
        wsh[mm][k] = w_qkv[((size_t)layer*64 + mm)*192 + which*64 + k];
    }
    __syncthreads();

    const int tm = tid >> 4, tn = tid & 15;
    float acc[4][4] = {};
    for (int k = 0; k < 64; k++) {
        const float a0 = as[tm*4+0][k];
        const float a1 = as[tm*4+1][k];
        const float a2 = as[tm*4+2][k];
        const float a3 = as[tm*4+3][k];
        const float4 w = *(const float4*)&wsh[k][tn*4];
        acc[0][0]+=a0*w.x; acc[0][1]+=a0*w.y; acc[0][2]+=a0*w.z; acc[0][3]+=a0*w.w;
        acc[1][0]+=a1*w.x; acc[1][1]+=a1*w.y; acc[1][2]+=a1*w.z; acc[1][3]+=a1*w.w;
        acc[2][0]+=a2*w.x; acc[2][1]+=a2*w.y; acc[2][2]+=a2*w.z; acc[2][3]+=a2*w.w;
        acc[3][0]+=a3*w.x; acc[3][1]+=a3*w.y; acc[3][2]+=a3*w.z; acc[3][3]+=a3*w.w;
    }

    float* dst = (which == 0) ? qb : (which == 1) ? kb : vb;
    const float scale = (which == 0) ? 0.25f : 1.0f;   // HEAD_DIM^-0.5
    const int hh = tn >> 2;
    const int dbase = (tn & 3) * 4;
    const float4 bv = *(const float4*)&b_qkv[(size_t)layer*192 + which*64 + tn*4];
    #pragma unroll
    for (int r = 0; r < 4; r++) {
        const int row = m0 + tm*4 + r;
        const int pos = row - bidx*NPOS;
        float4 o;
        o.x = (acc[r][0] + bv.x) * scale;
        o.y = (acc[r][1] + bv.y) * scale;
        o.z = (acc[r][2] + bv.z) * scale;
        o.w = (acc[r][3] + bv.w) * scale;
        *(float4*)&dst[(((size_t)bidx*NH + hh)*NPOS + pos)*HD + dbase] = o;
    }
}

// ---------------------------------------------------------------------------
// Neighborhood attention v5 (r14-proven): block = (bh, 4 query rows), k/v
// co-staged fp32 into LDS (141 KB) in one loop -> single barrier.
// blockIdx = it*8+bh keeps (b,h) per-XCD.
// ---------------------------------------------------------------------------
__global__ void __launch_bounds__(384, 1) nattn_kernel(
    const float* __restrict__ qb,
    const float* __restrict__ kb,
    const float* __restrict__ vb,
    const float* __restrict__ rpb,   // (2,4,13,13)
    const int layer,
    float* __restrict__ ao)          // (B,T,F,64)
{
    __shared__ float kv[2][10][88][20];   // 140.8 KB
    __shared__ float rp[169];
    const int blk = blockIdx.x;
    const int bh = blk & 7;          // XCD selector under round-robin dispatch
    const int it = blk >> 3;         // 0..31
    const int i0 = it*4;
    const int h  = bh & 3;
    const int bb = bh >> 2;
    const int tid = threadIdx.x;
    const int rs = min(max(i0-3, 0), T_-10);   // 10-row window start
    const float* kbase = kb + (size_t)bh*NPOS*HD;
    const float* vbase = vb + (size_t)bh*NPOS*HD;

    const bool act = (tid < 4*F_);
    const int isub = act ? (tid / F_) : 0;
    const int j    = act ? (tid - isub*F_) : 0;
    const int i    = i0 + isub;
    const int ihs  = min(max(i-3, 0), T_-7);
    const int ro   = ihs - rs;       // 0..3: local row offset
    const int cw   = min(max(j-3, 0), F_-7);

    float4 q0, q1, q2, q3;
    if (act) {
        const float4* qp = (const float4*)&qb[((size_t)bh*NPOS + i*F_ + j)*HD];
        q0 = qp[0]; q1 = qp[1]; q2 = qp[2]; q3 = qp[3];
    }
    for (int n = tid; n < 169; n += 384)
        rp[n] = rpb[((size_t)layer*NH + h)*169 + n];
    for (int n4 = tid; n4 < 10*88*4; n4 += 384) {
        const int d4   = n4 & 3;
        const int rest = n4 >> 2;
        const int c    = rest % 88;
        const int r    = rest / 88;
        const size_t goff = ((size_t)(rs+r)*F_ + c)*HD + d4*4;
        *(float4*)&kv[0][r][c][d4*4] = *(const float4*)&kbase[goff];
        *(float4*)&kv[1][r][c][d4*4] = *(const float4*)&vbase[goff];
    }
    __syncthreads();

    if (act) {
        float lg[49];
        #pragma unroll
        for (int ki = 0; ki < 7; ki++) {
            const int rh = ihs + ki - i + 6;
            #pragma unroll
            for (int kj = 0; kj < 7; kj++) {
                const float4* kp = (const float4*)&kv[0][ro+ki][cw+kj][0];
                const float4 k0 = kp[0], k1 = kp[1], k2 = kp[2], k3 = kp[3];
                float d = q0.x*k0.x + q0.y*k0.y + q0.z*k0.z + q0.w*k0.w
                        + q1.x*k1.x + q1.y*k1.y + q1.z*k1.z + q1.w*k1.w
                        + q2.x*k2.x + q2.y*k2.y + q2.z*k2.z + q2.w*k2.w
                        + q3.x*k3.x + q3.y*k3.y + q3.z*k3.z + q3.w*k3.w;
                lg[ki*7+kj] = d + rp[rh*13 + (cw + kj - j + 6)];
            }
        }
        float m = lg[0];
        #pragma unroll
        for (int n = 1; n < 49; n++) m = fmaxf(m, lg[n]);
        float ssum = 0.f;
        #pragma unroll
        for (int n = 0; n < 49; n++) { lg[n] = __expf(lg[n] - m); ssum += lg[n]; }
        const float inv = __builtin_amdgcn_rcpf(ssum);
        #pragma unroll
        for (int n = 0; n < 49; n++) lg[n] *= inv;

        float4 o0 = {0,0,0,0}, o1 = {0,0,0,0}, o2 = {0,0,0,0}, o3 = {0,0,0,0};
        #pragma unroll
        for (int ki = 0; ki < 7; ki++) {
            #pragma unroll
            for (int kj = 0; kj < 7; kj++) {
                const float a = lg[ki*7+kj];
                const float4* vp = (const float4*)&kv[1][ro+ki][cw+kj][0];
                const float4 v0 = vp[0], v1 = vp[1], v2 = vp[2], v3 = vp[3];
                o0.x += a*v0.x; o0.y += a*v0.y; o0.z += a*v0.z; o0.w += a*v0.w;
                o1.x += a*v1.x; o1.y += a*v1.y; o1.z += a*v1.z; o1.w += a*v1.w;
                o2.x += a*v2.x; o2.y += a*v2.y; o2.z += a*v2.z; o2.w += a*v2.w;
                o3.x += a*v3.x; o3.y += a*v3.y; o3.z += a*v3.z; o3.w += a*v3.w;
            }
        }
        float4* op = (float4*)&ao[(((size_t)bb*T_ + i)*F_ + j)*NU + h*HD];
        op[0]=o0; op[1]=o1; op[2]=o2; op[3]=o3;
    }
}

// ---------------------------------------------------------------------------
// proj + residual: out = hres + ain @ Wproj + b  (unchanged)
// ---------------------------------------------------------------------------
__global__ void __launch_bounds__(256, 2) proj_kernel(
    const float* __restrict__ ain,   // (NTOK,64)
    const float* __restrict__ hres,  // (NTOK,64)
    const float* __restrict__ w_proj,// (2,64,64)
    const float* __restrict__ b_proj,// (2,64)
    const int layer,
    float* __restrict__ outp)
{
    __shared__ float as[64][65];
    __shared__ float wsh[64][64];
    const int m0 = blockIdx.x * 64;
    const int tid = threadIdx.x;
    for (int n = tid; n < 64*64; n += 256) {
        const int mm = n >> 6, k = n & 63;
        as[mm][k]  = ain[((size_t)m0+mm)*64 + k];
        wsh[mm][k] = w_proj[(size_t)layer*4096 + n];
    }
    __syncthreads();
    const int tm = tid >> 4, tn = tid & 15;
    float acc[4][4] = {};
    for (int k = 0; k < 64; k++) {
        const float a0 = as[tm*4+0][k];
        const float a1 = as[tm*4+1][k];
        const float a2 = as[tm*4+2][k];
        const float a3 = as[tm*4+3][k];
        const float4 w = *(const float4*)&wsh[k][tn*4];
        acc[0][0]+=a0*w.x; acc[0][1]+=a0*w.y; acc[0][2]+=a0*w.z; acc[0][3]+=a0*w.w;
        acc[1][0]+=a1*w.x; acc[1][1]+=a1*w.y; acc[1][2]+=a1*w.z; acc[1][3]+=a1*w.w;
        acc[2][0]+=a2*w.x; acc[2][1]+=a2*w.y; acc[2][2]+=a2*w.z; acc[2][3]+=a2*w.w;
        acc[3][0]+=a3*w.x; acc[3][1]+=a3*w.y; acc[3][2]+=a3*w.z; acc[3][3]+=a3*w.w;
    }
    const float4 bv = *(const float4*)&b_proj[(size_t)layer*64 + tn*4];
    #pragma unroll
    for (int r = 0; r < 4; r++) {
        const int row = m0 + tm*4 + r;
        const float4 hv = *(const float4*)&hres[(size_t)row*64 + tn*4];
        float4 o;
        o.x = hv.x + acc[r][0] + bv.x;
        o.y = hv.y + acc[r][1] + bv.y;
        o.z = hv.z + acc[r][2] + bv.z;
        o.w = hv.w + acc[r][3] + bv.w;
        *(float4*)&outp[(size_t)row*64 + tn*4] = o;
    }
}

extern "C" void kernel_launch(void* const* d_in, const int* in_sizes, int n_in,
                              void* d_out, int out_size, void* d_ws, size_t ws_size,
                              hipStream_t stream) {
    const float* x      = (const float*)d_in[0];
    const int*   tarr   = (const int*)  d_in[1];
    const float* w_ih   = (const float*)d_in[2];
    const float* w_hh   = (const float*)d_in[3];
    const float* b_ih   = (const float*)d_in[4];
    const float* b_hh   = (const float*)d_in[5];
    const float* t_emb  = (const float*)d_in[6];
    const float* w_qkv  = (const float*)d_in[7];
    const float* b_qkv  = (const float*)d_in[8];
    const float* rpb    = (const float*)d_in[9];
    const float* w_proj = (const float*)d_in[10];
    const float* b_proj = (const float*)d_in[11];

    float* ws   = (float*)d_ws;
    const size_t CH = (size_t)NTOK * NU;   // 1441792 floats
    float* hcur = ws;                      // (B,T,F,64)
    float* h0   = ws + CH;                 // (NSEQ,T,64)
    float* G    = ws + 2*CH;               // (NSEQ,2,T,64) float2 == 4*CH floats
    float* qbuf = ws + 2*CH;               // overlays G after LSTM phase
    float* kbuf = ws + 3*CH;
    float* vbuf = ws + 4*CH;
    float* ao   = ws + 5*CH;
    float* outp = (float*)d_out;

    gg_kernel<0><<<dim3(NSEQ, T_/32), 256, 0, stream>>>(x,  w_ih, b_ih, b_hh, G);
    lstm_rec<0><<<NSEQ, 128, 0, stream>>>(G, w_hh, h0);
    gg_kernel<1><<<dim3(NSEQ, T_/32), 256, 0, stream>>>(h0, w_ih, b_ih, b_hh, G);
    lstm_rec<1><<<NSEQ, 128, 0, stream>>>(G, w_hh, hcur);

    for (int l = 0; l < 2; l++) {
        qkv_kernel<<<dim3(NTOK/64, 3), 256, 0, stream>>>(
            hcur, tarr, t_emb, w_qkv, b_qkv, l, qbuf, kbuf, vbuf);
        nattn_kernel<<<(T_/4)*8, 384, 0, stream>>>(
            qbuf, kbuf, vbuf, rpb, l, ao);
        proj_kernel<<<NTOK/64, 256, 0, stream>>>(
            ao, hcur, w_proj, b_proj, l, (l == 0) ? hcur : outp);
    }
}